// Round 5
// baseline (338.461 us; speedup 1.0000x reference)
//
#include <hip/hip_runtime.h>

#define SS 2048
#define DD 64
#define S2 0.18033688011112042f   // (1/sqrt(64)) * log2(e)

typedef __attribute__((ext_vector_type(4))) float f32x4;
typedef __attribute__((ext_vector_type(8))) short bfx8;
typedef __attribute__((ext_vector_type(4))) short bfx4;

__device__ __forceinline__ short f2bf(float f) {
    unsigned u = __builtin_bit_cast(unsigned, f);
    u += 0x7fffu + ((u >> 16) & 1u);   // RTNE
    return (short)(u >> 16);
}
__device__ __forceinline__ bfx8 pack8(f32x4 a, f32x4 b) {
    bfx8 r;
    r[0] = f2bf(a[0]); r[1] = f2bf(a[1]); r[2] = f2bf(a[2]); r[3] = f2bf(a[3]);
    r[4] = f2bf(b[0]); r[5] = f2bf(b[1]); r[6] = f2bf(b[2]); r[7] = f2bf(b[3]);
    return r;
}
__device__ __forceinline__ float bf2f(short s) {
    unsigned u = ((unsigned)(unsigned short)s) << 16;
    return __builtin_bit_cast(float, u);
}
// lgkm-only barrier: drains LDS ops, lets VMEM (NT stores, prefetches) stream across
__device__ __forceinline__ void bar_lg() {
    asm volatile("s_waitcnt lgkmcnt(0)\n\ts_barrier" ::: "memory");
}
// raw barrier: no waitcnt at all (all LDS reads already consumed pre-barrier)
__device__ __forceinline__ void bar_raw() {
    asm volatile("s_barrier" ::: "memory");
}

__global__ __launch_bounds__(512, 4) void pattn_kernel(
    const float* __restrict__ q, const float* __restrict__ k,
    const float* __restrict__ v, float* __restrict__ out,
    float* __restrict__ attn)
{
    const int tid = threadIdx.x;
    const int wid = tid >> 6, lane = tid & 63;
    const int c = lane & 15, g = lane >> 4;

    // XCD-grouped mapping: 512 blocks, blk%8 = XCD (round-robin heuristic).
    // XCD x owns heads 4x..4x+3 -> K+V fp32 of 4 heads = 4 MB = one L2.
    const int blk = blockIdx.x;
    const int bh  = (blk & 7) * 4 + ((blk >> 3) & 3);
    const int qt  = blk >> 5;                   // [0,16), 128 q-rows per block

    const long hoff  = (long)bh * SS * DD;
    const int  qbase = qt * 128 + wid * 16;
    const int  qrow  = qbase + c;

    // LDS pool: Kbuf0 [128][72] | Vt [64][136] (pass1: Kbuf1 overlay) | Wc [8][16][136]
    __shared__ __align__(16) short lds[35328];   // 70656 B -> 2 blocks/CU
    #define KLp(b, key, d)  (&lds[(b)*9216 + (key)*72 + (d)])
    #define VTp(d, key)     (&lds[9216 + (d)*136 + (key)])
    #define WCp(w, r, key)  (&lds[17920 + (w)*2176 + (r)*136 + (key)])

    // Q fragment (B-operand of swapped QK^T), pre-scaled by S2
    bfx8 bq0, bq1;
    {
        const float* qp = q + hoff + (long)qrow * DD + 8 * g;
        f32x4 x0 = *(const f32x4*)(qp)      * S2;
        f32x4 x1 = *(const f32x4*)(qp + 4)  * S2;
        f32x4 x2 = *(const f32x4*)(qp + 32) * S2;
        f32x4 x3 = *(const f32x4*)(qp + 36) * S2;
        bq0 = pack8(x0, x1);
        bq1 = pack8(x2, x3);
    }

    // --- staging split: issue loads early, pack+write late (T14) ---
    const int skey = tid >> 2, sdq = (tid & 3) << 4;        // K: 16 dims/thread
    const int vkq  = (tid & 31) << 2, vdg = (tid >> 5) << 2; // V: 4 keys x 4 dims

    f32x4 kr[4], vr[4];
    auto loadK = [&](int k0) {
        const float* kp = k + hoff + (long)(k0 + skey) * DD + sdq;
        kr[0] = *(const f32x4*)(kp);
        kr[1] = *(const f32x4*)(kp + 4);
        kr[2] = *(const f32x4*)(kp + 8);
        kr[3] = *(const f32x4*)(kp + 12);
    };
    auto writeK = [&](int b) {
        *(bfx8*)KLp(b, skey, sdq)     = pack8(kr[0], kr[1]);
        *(bfx8*)KLp(b, skey, sdq + 8) = pack8(kr[2], kr[3]);
    };
    auto loadV = [&](int k0) {
        const float* vp = v + hoff + (long)(k0 + vkq) * DD + vdg;
        vr[0] = *(const f32x4*)(vp);
        vr[1] = *(const f32x4*)(vp + DD);
        vr[2] = *(const f32x4*)(vp + 2 * DD);
        vr[3] = *(const f32x4*)(vp + 3 * DD);
    };
    auto writeV = [&]() {
        #pragma unroll
        for (int d = 0; d < 4; ++d) {
            bfx4 w;
            w[0] = f2bf(vr[0][d]); w[1] = f2bf(vr[1][d]);
            w[2] = f2bf(vr[2][d]); w[3] = f2bf(vr[3][d]);
            *(bfx4*)VTp(vdg + d, vkq) = w;
        }
    };

    // ---------------- pass 1: row sums, double-buffered K ----------------
    float lsum = 0.f;
    loadK(0); writeK(0);
    for (int it = 0; it < 16; ++it) {
        bar_lg();                        // stage(it) visible
        if (it < 15) loadK((it + 1) * 128);   // prefetch next (VMEM in flight)
        const int b = it & 1;
        #pragma unroll
        for (int T = 0; T < 8; ++T) {
            bfx8 kb0 = *(const bfx8*)KLp(b, T * 16 + c, 8 * g);
            bfx8 kb1 = *(const bfx8*)KLp(b, T * 16 + c, 32 + 8 * g);
            f32x4 s = {0.f, 0.f, 0.f, 0.f};
            s = __builtin_amdgcn_mfma_f32_16x16x32_bf16(kb0, bq0, s, 0, 0, 0);
            s = __builtin_amdgcn_mfma_f32_16x16x32_bf16(kb1, bq1, s, 0, 0, 0);
            lsum += __builtin_amdgcn_exp2f(s[0]);
            lsum += __builtin_amdgcn_exp2f(s[1]);
            lsum += __builtin_amdgcn_exp2f(s[2]);
            lsum += __builtin_amdgcn_exp2f(s[3]);
        }
        if (it < 15) writeK((it + 1) & 1);    // pack+write after compute
    }
    lsum += __shfl_xor(lsum, 16, 64);
    lsum += __shfl_xor(lsum, 32, 64);
    const float invl = 1.0f / lsum;
    bar_lg();   // protect K/V region before pass-2 staging

    // ---------------- pass 2: attn (coalesced NT) + PV ----------------
    f32x4 acc[4];
    #pragma unroll
    for (int i = 0; i < 4; ++i) acc[i] = (f32x4){0.f, 0.f, 0.f, 0.f};

    float* attnw = attn + (long)bh * SS * SS + (long)qbase * SS;

    loadK(0); loadV(0);
    for (int it = 0; it < 16; ++it) {
        const int k0 = it * 128;
        writeK(0); writeV();
        bar_lg();                            // stage visible (VMEM still streams)
        if (it < 15) { loadK(k0 + 128); loadV(k0 + 128); }  // prefetch next

        #pragma unroll
        for (int G = 0; G < 4; ++G) {
            #pragma unroll
            for (int t = 0; t < 2; ++t) {
                const int kb = G * 32 + t * 16;
                bfx8 kb0 = *(const bfx8*)KLp(0, kb + c, 8 * g);
                bfx8 kb1 = *(const bfx8*)KLp(0, kb + c, 32 + 8 * g);
                f32x4 s = {0.f, 0.f, 0.f, 0.f};
                s = __builtin_amdgcn_mfma_f32_16x16x32_bf16(kb0, bq0, s, 0, 0, 0);
                s = __builtin_amdgcn_mfma_f32_16x16x32_bf16(kb1, bq1, s, 0, 0, 0);
                bfx4 wp;
                wp[0] = f2bf(__builtin_amdgcn_exp2f(s[0]) * invl);
                wp[1] = f2bf(__builtin_amdgcn_exp2f(s[1]) * invl);
                wp[2] = f2bf(__builtin_amdgcn_exp2f(s[2]) * invl);
                wp[3] = f2bf(__builtin_amdgcn_exp2f(s[3]) * invl);
                *(bfx4*)WCp(wid, c, kb + 4 * g) = wp;
            }
            // PV on this 32-key group (wave-private Wc, lgkm-ordered)
            bfx8 wb = *(const bfx8*)WCp(wid, c, G * 32 + 8 * g);
            #pragma unroll
            for (int ds = 0; ds < 4; ++ds) {
                bfx8 va = *(const bfx8*)VTp(ds * 16 + c, G * 32 + 8 * g);
                acc[ds] = __builtin_amdgcn_mfma_f32_16x16x32_bf16(va, wb, acc[ds], 0, 0, 0);
            }
        }

        // coalesced NT emit: 16 rows x 512 B contiguous per iter (own-wave Wc)
        {
            const int col8 = c * 8;
            #pragma unroll
            for (int rg = 0; rg < 4; ++rg) {
                const int r = rg * 4 + g;
                bfx8 w8 = *(const bfx8*)WCp(wid, r, col8);
                f32x4 lo, hi;
                lo[0] = bf2f(w8[0]); lo[1] = bf2f(w8[1]);
                lo[2] = bf2f(w8[2]); lo[3] = bf2f(w8[3]);
                hi[0] = bf2f(w8[4]); hi[1] = bf2f(w8[5]);
                hi[2] = bf2f(w8[6]); hi[3] = bf2f(w8[7]);
                float* dst = attnw + (long)r * SS + k0 + col8;
                __builtin_nontemporal_store(lo, (f32x4*)dst);
                __builtin_nontemporal_store(hi, (f32x4*)(dst + 4));
            }
        }
        bar_raw();   // all waves done reading Kl/Vt; stores keep streaming
    }

    // ---------------- row-norm preconditioning + output ----------------
    float ssq = 0.f;
    #pragma unroll
    for (int ds = 0; ds < 4; ++ds)
        #pragma unroll
        for (int r = 0; r < 4; ++r)
            ssq += acc[ds][r] * acc[ds][r];
    ssq += __shfl_xor(ssq, 16, 64);
    ssq += __shfl_xor(ssq, 32, 64);
    const float inv = 1.0f / (sqrtf(ssq) + 1e-8f);

    float* op = out + hoff + (long)qrow * DD;
    #pragma unroll
    for (int ds = 0; ds < 4; ++ds) {
        f32x4 o;
        o[0] = acc[ds][0] * inv; o[1] = acc[ds][1] * inv;
        o[2] = acc[ds][2] * inv; o[3] = acc[ds][3] * inv;
        *(f32x4*)&op[ds * 16 + 4 * g] = o;
    }
}

extern "C" void kernel_launch(void* const* d_in, const int* in_sizes, int n_in,
                              void* d_out, int out_size, void* d_ws, size_t ws_size,
                              hipStream_t stream) {
    const float* q = (const float*)d_in[0];
    const float* k = (const float*)d_in[1];
    const float* v = (const float*)d_in[2];
    float* out  = (float*)d_out;
    float* attn = out + (long)2 * 16 * SS * DD;   // second tuple element
    dim3 grid(512), block(512);
    hipLaunchKernelGGL(pattn_kernel, grid, block, 0, stream, q, k, v, out, attn);
}

// Round 6
// 245.479 us; speedup vs baseline: 1.3788x; 1.3788x over previous
//
#include <hip/hip_runtime.h>

#define SS 2048
#define DD 64
#define S2 0.18033688011112042f   // (1/sqrt(64)) * log2(e)

typedef __attribute__((ext_vector_type(4))) float f32x4;
typedef __attribute__((ext_vector_type(8))) short bfx8;
typedef __attribute__((ext_vector_type(4))) short bfx4;

__device__ __forceinline__ short f2bf(float f) {
    unsigned u = __builtin_bit_cast(unsigned, f);
    u += 0x7fffu + ((u >> 16) & 1u);   // RTNE
    return (short)(u >> 16);
}
__device__ __forceinline__ bfx8 pack8(f32x4 a, f32x4 b) {
    bfx8 r;
    r[0] = f2bf(a[0]); r[1] = f2bf(a[1]); r[2] = f2bf(a[2]); r[3] = f2bf(a[3]);
    r[4] = f2bf(b[0]); r[5] = f2bf(b[1]); r[6] = f2bf(b[2]); r[7] = f2bf(b[7-4]);
    r[7] = f2bf(b[3]);
    return r;
}
__device__ __forceinline__ float bf2f(short s) {
    unsigned u = ((unsigned)(unsigned short)s) << 16;
    return __builtin_bit_cast(float, u);
}

__global__ __launch_bounds__(256) void pattn_kernel(
    const float* __restrict__ q, const float* __restrict__ k,
    const float* __restrict__ v, float* __restrict__ out,
    float* __restrict__ attn)
{
    // XCD-grouped mapping (validated r5: FETCH 367->35 MB):
    // xcd = blk&7 owns heads 4*xcd..4*xcd+3; K+V of 4 heads = 4 MB -> one L2.
    const int blk = blockIdx.x;
    const int bh  = (blk & 7) * 4 + ((blk >> 3) & 3);
    const int qt  = blk >> 5;          // 0..31, q tile of 64 rows
    const int tid = threadIdx.x;
    const int wid = tid >> 6, lane = tid & 63;
    const int c = lane & 15, g = lane >> 4;

    const long hoff = (long)bh * SS * DD;
    const int  qrow = qt * 64 + wid * 16 + c;   // this lane's q row

    __shared__ __align__(16) short Kl[128][72];     // [key][d]        18432 B
    __shared__ __align__(16) short Vt[64][136];     // [d][key]        17408 B
    __shared__ __align__(16) short Wc[4][16][136];  // wave [q][key128] 17408 B

    // Q fragment (B-operand of swapped QK^T), pre-scaled by S2
    bfx8 bq0, bq1;
    {
        const float* qp = q + hoff + (long)qrow * DD + 8 * g;
        f32x4 x0 = *(const f32x4*)(qp)      * S2;
        f32x4 x1 = *(const f32x4*)(qp + 4)  * S2;
        f32x4 x2 = *(const f32x4*)(qp + 32) * S2;
        f32x4 x3 = *(const f32x4*)(qp + 36) * S2;
        bq0 = pack8(x0, x1);
        bq1 = pack8(x2, x3);
    }

    auto stageK = [&](int k0) {
        const int key = tid >> 1, dh = (tid & 1) << 5;
        const float* kp = k + hoff + (long)(k0 + key) * DD + dh;
        f32x4 a0 = *(const f32x4*)(kp);
        f32x4 a1 = *(const f32x4*)(kp + 4);
        f32x4 a2 = *(const f32x4*)(kp + 8);
        f32x4 a3 = *(const f32x4*)(kp + 12);
        f32x4 a4 = *(const f32x4*)(kp + 16);
        f32x4 a5 = *(const f32x4*)(kp + 20);
        f32x4 a6 = *(const f32x4*)(kp + 24);
        f32x4 a7 = *(const f32x4*)(kp + 28);
        *(bfx8*)&Kl[key][dh + 0]  = pack8(a0, a1);
        *(bfx8*)&Kl[key][dh + 8]  = pack8(a2, a3);
        *(bfx8*)&Kl[key][dh + 16] = pack8(a4, a5);
        *(bfx8*)&Kl[key][dh + 24] = pack8(a6, a7);
    };

    auto stageV = [&](int k0) {
        const int kq = (tid & 31) * 4, dg = (tid >> 5) * 8;
        const float* vp = v + hoff + (long)(k0 + kq) * DD + dg;
        f32x4 r0a = *(const f32x4*)(vp),        r0b = *(const f32x4*)(vp + 4);
        f32x4 r1a = *(const f32x4*)(vp + DD),   r1b = *(const f32x4*)(vp + DD + 4);
        f32x4 r2a = *(const f32x4*)(vp + 2*DD), r2b = *(const f32x4*)(vp + 2*DD + 4);
        f32x4 r3a = *(const f32x4*)(vp + 3*DD), r3b = *(const f32x4*)(vp + 3*DD + 4);
        #pragma unroll
        for (int d = 0; d < 4; ++d) {
            bfx4 w;
            w[0] = f2bf(r0a[d]); w[1] = f2bf(r1a[d]);
            w[2] = f2bf(r2a[d]); w[3] = f2bf(r3a[d]);
            *(bfx4*)&Vt[dg + d][kq] = w;
        }
        #pragma unroll
        for (int d = 0; d < 4; ++d) {
            bfx4 w;
            w[0] = f2bf(r0b[d]); w[1] = f2bf(r1b[d]);
            w[2] = f2bf(r2b[d]); w[3] = f2bf(r3b[d]);
            *(bfx4*)&Vt[dg + 4 + d][kq] = w;
        }
    };

    // ---------------- pass 1: row sums of exp2(score) ----------------
    float lsum = 0.f;
    for (int k0 = 0; k0 < SS; k0 += 128) {
        stageK(k0);
        __syncthreads();
        #pragma unroll
        for (int T = 0; T < 8; ++T) {
            bfx8 kb0 = *(const bfx8*)&Kl[T * 16 + c][8 * g];
            bfx8 kb1 = *(const bfx8*)&Kl[T * 16 + c][32 + 8 * g];
            f32x4 s = {0.f, 0.f, 0.f, 0.f};
            s = __builtin_amdgcn_mfma_f32_16x16x32_bf16(kb0, bq0, s, 0, 0, 0);
            s = __builtin_amdgcn_mfma_f32_16x16x32_bf16(kb1, bq1, s, 0, 0, 0);
            lsum += __builtin_amdgcn_exp2f(s[0]);
            lsum += __builtin_amdgcn_exp2f(s[1]);
            lsum += __builtin_amdgcn_exp2f(s[2]);
            lsum += __builtin_amdgcn_exp2f(s[3]);
        }
        __syncthreads();
    }
    lsum += __shfl_xor(lsum, 16, 64);
    lsum += __shfl_xor(lsum, 32, 64);
    const float invl = 1.0f / lsum;

    // ---------------- pass 2: W (LDS bf16) + PV + coalesced attn store ----------------
    f32x4 acc[4];
    #pragma unroll
    for (int i = 0; i < 4; ++i) acc[i] = (f32x4){0.f, 0.f, 0.f, 0.f};

    float* attnw = attn + (long)bh * SS * SS + (long)(qt * 64 + wid * 16) * SS;

    for (int k0 = 0; k0 < SS; k0 += 128) {
        stageK(k0);
        stageV(k0);
        __syncthreads();
        #pragma unroll
        for (int G = 0; G < 4; ++G) {
            #pragma unroll
            for (int t = 0; t < 2; ++t) {
                const int kb = G * 32 + t * 16;
                bfx8 kb0 = *(const bfx8*)&Kl[kb + c][8 * g];
                bfx8 kb1 = *(const bfx8*)&Kl[kb + c][32 + 8 * g];
                f32x4 s = {0.f, 0.f, 0.f, 0.f};
                s = __builtin_amdgcn_mfma_f32_16x16x32_bf16(kb0, bq0, s, 0, 0, 0);
                s = __builtin_amdgcn_mfma_f32_16x16x32_bf16(kb1, bq1, s, 0, 0, 0);
                bfx4 wp;
                wp[0] = f2bf(__builtin_amdgcn_exp2f(s[0]) * invl);
                wp[1] = f2bf(__builtin_amdgcn_exp2f(s[1]) * invl);
                wp[2] = f2bf(__builtin_amdgcn_exp2f(s[2]) * invl);
                wp[3] = f2bf(__builtin_amdgcn_exp2f(s[3]) * invl);
                *(bfx4*)&Wc[wid][c][kb + 4 * g] = wp;
            }
            // PV over this 32-key group (wave-private Wc: lgkmcnt-ordered, no barrier)
            bfx8 wb = *(const bfx8*)&Wc[wid][c][G * 32 + 8 * g];
            #pragma unroll
            for (int ds = 0; ds < 4; ++ds) {
                bfx8 va = *(const bfx8*)&Vt[ds * 16 + c][G * 32 + 8 * g];
                acc[ds] = __builtin_amdgcn_mfma_f32_16x16x32_bf16(va, wb, acc[ds], 0, 0, 0);
            }
        }
        __syncthreads();   // all waves done with Kl/Vt (next iter restages)

        // coalesced NT emit: each instruction = 32 lanes x 16B fully contiguous
        // (two rows per instruction; per row 512 B contiguous burst)
        {
            const int half = lane >> 5;          // 0,1 -> row parity
            const int col  = (lane & 31) * 4;    // float col within 128
            #pragma unroll
            for (int rg = 0; rg < 8; ++rg) {
                const int r = rg * 2 + half;
                bfx4 w4 = *(const bfx4*)&Wc[wid][r][col];
                f32x4 o;
                o[0] = bf2f(w4[0]); o[1] = bf2f(w4[1]);
                o[2] = bf2f(w4[2]); o[3] = bf2f(w4[3]);
                __builtin_nontemporal_store(o, (f32x4*)(attnw + (long)r * SS + k0 + col));
            }
        }
    }

    // ---------------- row-norm preconditioning + output ----------------
    float ssq = 0.f;
    #pragma unroll
    for (int ds = 0; ds < 4; ++ds)
        #pragma unroll
        for (int r = 0; r < 4; ++r)
            ssq += acc[ds][r] * acc[ds][r];
    ssq += __shfl_xor(ssq, 16, 64);
    ssq += __shfl_xor(ssq, 32, 64);
    const float inv = 1.0f / (sqrtf(ssq) + 1e-8f);

    float* op = out + hoff + (long)qrow * DD;
    #pragma unroll
    for (int ds = 0; ds < 4; ++ds) {
        f32x4 o;
        o[0] = acc[ds][0] * inv; o[1] = acc[ds][1] * inv;
        o[2] = acc[ds][2] * inv; o[3] = acc[ds][3] * inv;
        *(f32x4*)&op[ds * 16 + 4 * g] = o;
    }
}

extern "C" void kernel_launch(void* const* d_in, const int* in_sizes, int n_in,
                              void* d_out, int out_size, void* d_ws, size_t ws_size,
                              hipStream_t stream) {
    const float* q = (const float*)d_in[0];
    const float* k = (const float*)d_in[1];
    const float* v = (const float*)d_in[2];
    float* out  = (float*)d_out;
    float* attn = out + (long)2 * 16 * SS * DD;   // second tuple element
    dim3 grid(1024), block(256);
    hipLaunchKernelGGL(pattn_kernel, grid, block, 0, stream, q, k, v, out, attn);
}

// Round 7
// 221.658 us; speedup vs baseline: 1.5270x; 1.1075x over previous
//
#include <hip/hip_runtime.h>

#define SS 2048
#define DD 64
#define S2 0.18033688011112042f   // (1/sqrt(64)) * log2(e)

typedef __attribute__((ext_vector_type(4))) float f32x4;
typedef __attribute__((ext_vector_type(8))) short bfx8;
typedef __attribute__((ext_vector_type(4))) short bfx4;

__device__ __forceinline__ short f2bf(float f) {
    unsigned u = __builtin_bit_cast(unsigned, f);
    u += 0x7fffu + ((u >> 16) & 1u);   // RTNE
    return (short)(u >> 16);
}
__device__ __forceinline__ bfx8 pack8(f32x4 a, f32x4 b) {
    bfx8 r;
    r[0] = f2bf(a[0]); r[1] = f2bf(a[1]); r[2] = f2bf(a[2]); r[3] = f2bf(a[3]);
    r[4] = f2bf(b[0]); r[5] = f2bf(b[1]); r[6] = f2bf(b[2]); r[7] = f2bf(b[3]);
    return r;
}
__device__ __forceinline__ float bf2f(short s) {
    unsigned u = ((unsigned)(unsigned short)s) << 16;
    return __builtin_bit_cast(float, u);
}
// stage-visible barrier: drain own LDS ops, then barrier (VMEM streams across)
__device__ __forceinline__ void bar_lg() {
    asm volatile("s_waitcnt lgkmcnt(0)\n\ts_barrier" ::: "memory");
    __builtin_amdgcn_sched_barrier(0);
}
// end-of-compute barrier: no waitcnt (all LDS results already consumed)
__device__ __forceinline__ void bar_raw() {
    asm volatile("s_barrier" ::: "memory");
    __builtin_amdgcn_sched_barrier(0);
}
// wait for prefetch loads only: the N youngest VMEM ops (NT stores) may remain
__device__ __forceinline__ void wait_vm8() {
    asm volatile("s_waitcnt vmcnt(8)" ::: "memory");
    __builtin_amdgcn_sched_barrier(0);
}
__device__ __forceinline__ void wait_vm0() {
    asm volatile("s_waitcnt vmcnt(0)" ::: "memory");
    __builtin_amdgcn_sched_barrier(0);
}

__global__ __launch_bounds__(256, 3) void pattn_kernel(
    const float* __restrict__ q, const float* __restrict__ k,
    const float* __restrict__ v, float* __restrict__ out,
    float* __restrict__ attn)
{
    // XCD-grouped mapping (validated r5: FETCH 367->35 MB)
    const int blk = blockIdx.x;
    const int bh  = (blk & 7) * 4 + ((blk >> 3) & 3);
    const int qt  = blk >> 5;          // 0..31, q tile of 64 rows
    const int tid = threadIdx.x;
    const int wid = tid >> 6, lane = tid & 63;
    const int c = lane & 15, g = lane >> 4;

    const long hoff = (long)bh * SS * DD;
    const int  qrow = qt * 64 + wid * 16 + c;

    __shared__ __align__(16) short Kl[128][72];     // 18432 B
    __shared__ __align__(16) short Vt[64][136];     // 17408 B
    __shared__ __align__(16) short Wc[4][16][136];  // 17408 B

    // Q fragment (B-operand of swapped QK^T), pre-scaled by S2
    bfx8 bq0, bq1;
    {
        const float* qp = q + hoff + (long)qrow * DD + 8 * g;
        f32x4 x0 = *(const f32x4*)(qp)      * S2;
        f32x4 x1 = *(const f32x4*)(qp + 4)  * S2;
        f32x4 x2 = *(const f32x4*)(qp + 32) * S2;
        f32x4 x3 = *(const f32x4*)(qp + 36) * S2;
        bq0 = pack8(x0, x1);
        bq1 = pack8(x2, x3);
    }

    // T14 staging: loads held in regs across compute, written after barrier
    const int skey = tid >> 1, sdh = (tid & 1) << 5;   // K: 32 dims/thread
    const int vkq  = (tid & 31) * 4, vdg = (tid >> 5) * 8;  // V: 4 keys x 8 dims
    f32x4 kr[8], vr[8];

    auto loadK = [&](int k0) {
        const float* kp = k + hoff + (long)(k0 + skey) * DD + sdh;
        #pragma unroll
        for (int i = 0; i < 8; ++i) kr[i] = *(const f32x4*)(kp + 4 * i);
    };
    auto writeK = [&]() {
        *(bfx8*)&Kl[skey][sdh + 0]  = pack8(kr[0], kr[1]);
        *(bfx8*)&Kl[skey][sdh + 8]  = pack8(kr[2], kr[3]);
        *(bfx8*)&Kl[skey][sdh + 16] = pack8(kr[4], kr[5]);
        *(bfx8*)&Kl[skey][sdh + 24] = pack8(kr[6], kr[7]);
    };
    auto loadV = [&](int k0) {
        const float* vp = v + hoff + (long)(k0 + vkq) * DD + vdg;
        #pragma unroll
        for (int r = 0; r < 4; ++r) {
            vr[2 * r]     = *(const f32x4*)(vp + r * DD);
            vr[2 * r + 1] = *(const f32x4*)(vp + r * DD + 4);
        }
    };
    auto writeV = [&]() {
        #pragma unroll
        for (int d = 0; d < 4; ++d) {
            bfx4 w;
            w[0] = f2bf(vr[0][d]); w[1] = f2bf(vr[2][d]);
            w[2] = f2bf(vr[4][d]); w[3] = f2bf(vr[6][d]);
            *(bfx4*)&Vt[vdg + d][vkq] = w;
        }
        #pragma unroll
        for (int d = 0; d < 4; ++d) {
            bfx4 w;
            w[0] = f2bf(vr[1][d]); w[1] = f2bf(vr[3][d]);
            w[2] = f2bf(vr[5][d]); w[3] = f2bf(vr[7][d]);
            *(bfx4*)&Vt[vdg + 4 + d][vkq] = w;
        }
    };

    // ---------------- pass 1: row sums of exp2(score) ----------------
    float lsum = 0.f;
    loadK(0); wait_vm0(); writeK();
    for (int it = 0; it < 16; ++it) {
        bar_lg();                               // stage(it) visible
        if (it < 15) loadK((it + 1) * 128);     // prefetch flies during compute
        #pragma unroll
        for (int T = 0; T < 8; ++T) {
            bfx8 kb0 = *(const bfx8*)&Kl[T * 16 + c][8 * g];
            bfx8 kb1 = *(const bfx8*)&Kl[T * 16 + c][32 + 8 * g];
            f32x4 s = {0.f, 0.f, 0.f, 0.f};
            s = __builtin_amdgcn_mfma_f32_16x16x32_bf16(kb0, bq0, s, 0, 0, 0);
            s = __builtin_amdgcn_mfma_f32_16x16x32_bf16(kb1, bq1, s, 0, 0, 0);
            lsum += __builtin_amdgcn_exp2f(s[0]);
            lsum += __builtin_amdgcn_exp2f(s[1]);
            lsum += __builtin_amdgcn_exp2f(s[2]);
            lsum += __builtin_amdgcn_exp2f(s[3]);
        }
        if (it < 15) wait_vm0();                // prefetch landed (under compute)
        bar_raw();                              // all waves done reading Kl
        if (it < 15) writeK();
    }
    lsum += __shfl_xor(lsum, 16, 64);
    lsum += __shfl_xor(lsum, 32, 64);
    const float invl = 1.0f / lsum;

    // ---------------- pass 2: W (LDS bf16) + PV + coalesced NT attn ----------------
    f32x4 acc[4];
    #pragma unroll
    for (int i = 0; i < 4; ++i) acc[i] = (f32x4){0.f, 0.f, 0.f, 0.f};

    float* attnw = attn + (long)bh * SS * SS + (long)(qt * 64 + wid * 16) * SS;

    loadK(0); loadV(0);
    wait_vm0();
    bar_raw();                 // pass-1 readers of Kl all past (last bar_raw had no write)
    writeK(); writeV();
    for (int it = 0; it < 16; ++it) {
        const int k0 = it * 128;
        bar_lg();                               // stage(it) visible
        if (it < 15) { loadK(k0 + 128); loadV(k0 + 128); }  // 16 loads in flight

        #pragma unroll
        for (int G = 0; G < 4; ++G) {
            #pragma unroll
            for (int t = 0; t < 2; ++t) {
                const int kb = G * 32 + t * 16;
                bfx8 kb0 = *(const bfx8*)&Kl[kb + c][8 * g];
                bfx8 kb1 = *(const bfx8*)&Kl[kb + c][32 + 8 * g];
                f32x4 s = {0.f, 0.f, 0.f, 0.f};
                s = __builtin_amdgcn_mfma_f32_16x16x32_bf16(kb0, bq0, s, 0, 0, 0);
                s = __builtin_amdgcn_mfma_f32_16x16x32_bf16(kb1, bq1, s, 0, 0, 0);
                bfx4 wp;
                wp[0] = f2bf(__builtin_amdgcn_exp2f(s[0]) * invl);
                wp[1] = f2bf(__builtin_amdgcn_exp2f(s[1]) * invl);
                wp[2] = f2bf(__builtin_amdgcn_exp2f(s[2]) * invl);
                wp[3] = f2bf(__builtin_amdgcn_exp2f(s[3]) * invl);
                *(bfx4*)&Wc[wid][c][kb + 4 * g] = wp;
            }
            // PV on this 32-key group (wave-private Wc, lgkm-ordered)
            bfx8 wb = *(const bfx8*)&Wc[wid][c][G * 32 + 8 * g];
            #pragma unroll
            for (int ds = 0; ds < 4; ++ds) {
                bfx8 va = *(const bfx8*)&Vt[ds * 16 + c][G * 32 + 8 * g];
                acc[ds] = __builtin_amdgcn_mfma_f32_16x16x32_bf16(va, wb, acc[ds], 0, 0, 0);
            }
        }

        // coalesced NT emit: 32 lanes x 16B contiguous per instruction
        {
            const int half = lane >> 5;
            const int col  = (lane & 31) * 4;
            #pragma unroll
            for (int rg = 0; rg < 8; ++rg) {
                const int r = rg * 2 + half;
                bfx4 w4 = *(const bfx4*)&Wc[wid][r][col];
                f32x4 o;
                o[0] = bf2f(w4[0]); o[1] = bf2f(w4[1]);
                o[2] = bf2f(w4[2]); o[3] = bf2f(w4[3]);
                __builtin_nontemporal_store(o, (f32x4*)(attnw + (long)r * SS + k0 + col));
            }
        }

        if (it < 15) {
            wait_vm8();     // 16 prefetch loads retired; 8 NT stores keep streaming
            bar_raw();      // all waves done reading Kl/Vt
            writeK(); writeV();
        }
    }

    // ---------------- row-norm preconditioning + output ----------------
    float ssq = 0.f;
    #pragma unroll
    for (int ds = 0; ds < 4; ++ds)
        #pragma unroll
        for (int r = 0; r < 4; ++r)
            ssq += acc[ds][r] * acc[ds][r];
    ssq += __shfl_xor(ssq, 16, 64);
    ssq += __shfl_xor(ssq, 32, 64);
    const float inv = 1.0f / (sqrtf(ssq) + 1e-8f);

    float* op = out + hoff + (long)qrow * DD;
    #pragma unroll
    for (int ds = 0; ds < 4; ++ds) {
        f32x4 o;
        o[0] = acc[ds][0] * inv; o[1] = acc[ds][1] * inv;
        o[2] = acc[ds][2] * inv; o[3] = acc[ds][3] * inv;
        *(f32x4*)&op[ds * 16 + 4 * g] = o;
    }
}

extern "C" void kernel_launch(void* const* d_in, const int* in_sizes, int n_in,
                              void* d_out, int out_size, void* d_ws, size_t ws_size,
                              hipStream_t stream) {
    const float* q = (const float*)d_in[0];
    const float* k = (const float*)d_in[1];
    const float* v = (const float*)d_in[2];
    float* out  = (float*)d_out;
    float* attn = out + (long)2 * 16 * SS * DD;   // second tuple element
    dim3 grid(1024), block(256);
    hipLaunchKernelGGL(pattn_kernel, grid, block, 0, stream, q, k, v, out, attn);
}

// Round 8
// 192.032 us; speedup vs baseline: 1.7625x; 1.1543x over previous
//
#include <hip/hip_runtime.h>

#define SS 2048
#define DD 64
#define S2 0.18033688011112042f   // (1/sqrt(64)) * log2(e)

typedef __attribute__((ext_vector_type(4))) float f32x4;
typedef __attribute__((ext_vector_type(8))) short bfx8;
typedef __attribute__((ext_vector_type(4))) short bfx4;

__device__ __forceinline__ short f2bf(float f) {
    unsigned u = __builtin_bit_cast(unsigned, f);
    u += 0x7fffu + ((u >> 16) & 1u);   // RTNE
    return (short)(u >> 16);
}
__device__ __forceinline__ bfx8 pack8(f32x4 a, f32x4 b) {
    bfx8 r;
    r[0] = f2bf(a[0]); r[1] = f2bf(a[1]); r[2] = f2bf(a[2]); r[3] = f2bf(a[3]);
    r[4] = f2bf(b[0]); r[5] = f2bf(b[1]); r[6] = f2bf(b[2]); r[7] = f2bf(b[3]);
    return r;
}
__device__ __forceinline__ float bf2f(short s) {
    unsigned u = ((unsigned)(unsigned short)s) << 16;
    return __builtin_bit_cast(float, u);
}
__device__ __forceinline__ void bar_raw() {
    asm volatile("s_barrier" ::: "memory");
    __builtin_amdgcn_sched_barrier(0);
}
__device__ __forceinline__ void wait_vm0() {
    asm volatile("s_waitcnt vmcnt(0)" ::: "memory");
    __builtin_amdgcn_sched_barrier(0);
}
__device__ __forceinline__ void wait_vm2() {
    asm volatile("s_waitcnt vmcnt(2)" ::: "memory");
    __builtin_amdgcn_sched_barrier(0);
}
__device__ __forceinline__ void wait_vm8() {
    asm volatile("s_waitcnt vmcnt(8)" ::: "memory");
    __builtin_amdgcn_sched_barrier(0);
}
// async global->LDS, 16B per lane; lds dest = wave-uniform base + lane*16
__device__ __forceinline__ void gload16(const void* g, void* l) {
    __builtin_amdgcn_global_load_lds(
        (const __attribute__((address_space(1))) unsigned*)g,
        (__attribute__((address_space(3))) unsigned*)l, 16, 0, 0);
}

// ================= pre-kernel: K -> bf16 [key][64], V -> bf16^T [d][key] =================
// Both stored granule-swizzled: 16B granule at in-row byte p holds original bytes p^((row&3)<<5).
__global__ __launch_bounds__(256) void prep_kernel(
    const float* __restrict__ k, const float* __restrict__ v,
    short* __restrict__ kbf, short* __restrict__ vtbf)
{
    const int blk = blockIdx.x;          // 512 = 32 bh x 16 chunks of 128 keys
    const int bh = blk >> 4, kc = blk & 15;
    const int tid = threadIdx.x;
    const long hoff = (long)bh * SS * DD;

    // ---- K convert (swizzled within each 128B key-row) ----
    {
        const int key = tid >> 1, h = tid & 1;
        const float* kp = k + hoff + (long)(kc * 128 + key) * DD + h * 32;
        char* krow = (char*)kbf + ((long)bh * SS + kc * 128 + key) * 128;
        const int x = (key & 3) << 5;
        #pragma unroll
        for (int i = 0; i < 4; ++i) {
            f32x4 a = *(const f32x4*)(kp + i * 8);
            f32x4 b = *(const f32x4*)(kp + i * 8 + 4);
            *(bfx8*)(krow + ((h * 64 + i * 16) ^ x)) = pack8(a, b);
        }
    }

    // ---- V transpose via LDS ----
    __shared__ __align__(16) short Vl[64][136];
    {
        const int kq = (tid & 31) * 4, dg = (tid >> 5) * 8;
        const float* vp = v + hoff + (long)(kc * 128 + kq) * DD + dg;
        f32x4 r0a = *(const f32x4*)(vp),        r0b = *(const f32x4*)(vp + 4);
        f32x4 r1a = *(const f32x4*)(vp + DD),   r1b = *(const f32x4*)(vp + DD + 4);
        f32x4 r2a = *(const f32x4*)(vp + 2*DD), r2b = *(const f32x4*)(vp + 2*DD + 4);
        f32x4 r3a = *(const f32x4*)(vp + 3*DD), r3b = *(const f32x4*)(vp + 3*DD + 4);
        #pragma unroll
        for (int d = 0; d < 4; ++d) {
            bfx4 w;
            w[0] = f2bf(r0a[d]); w[1] = f2bf(r1a[d]);
            w[2] = f2bf(r2a[d]); w[3] = f2bf(r3a[d]);
            *(bfx4*)&Vl[dg + d][kq] = w;
        }
        #pragma unroll
        for (int d = 0; d < 4; ++d) {
            bfx4 w;
            w[0] = f2bf(r0b[d]); w[1] = f2bf(r1b[d]);
            w[2] = f2bf(r2b[d]); w[3] = f2bf(r3b[d]);
            *(bfx4*)&Vl[dg + 4 + d][kq] = w;
        }
    }
    __syncthreads();
    {
        const int d = tid >> 2, quar = tid & 3;
        char* vrow = (char*)vtbf + ((long)bh * 64 + d) * 4096 + kc * 256;
        const int x = (d & 3) << 5;
        #pragma unroll
        for (int i = 0; i < 4; ++i) {
            bfx8 w = *(const bfx8*)((const char*)&Vl[d][0] + quar * 64 + i * 16);
            *(bfx8*)(vrow + ((quar * 64 + i * 16) ^ x)) = w;
        }
    }
}

// ================= main kernel: gl_lds-staged, double-buffered 64-key tiles =================
__global__ __launch_bounds__(256, 3) void pattn_main(
    const float* __restrict__ q, const short* __restrict__ kbf,
    const short* __restrict__ vtbf, float* __restrict__ out,
    float* __restrict__ attn)
{
    // XCD-grouped mapping (validated r5)
    const int blk = blockIdx.x;
    const int bh  = (blk & 7) * 4 + ((blk >> 3) & 3);
    const int qt  = blk >> 5;
    const int tid = threadIdx.x;
    const int wid = tid >> 6, lane = tid & 63;
    const int c = lane & 15, g = lane >> 4;

    __shared__ __align__(16) short Kl[2][64][64];   // 16384 B
    __shared__ __align__(16) short Vt[2][64][64];   // 16384 B
    __shared__ __align__(16) short Wc[4][16][80];   // 10240 B  -> 43008 B, 3 blk/CU

    const long hoff = (long)bh * SS * DD;
    const int  qrow = qt * 64 + wid * 16 + c;

    bfx8 bq0, bq1;
    {
        const float* qp = q + hoff + (long)qrow * DD + 8 * g;
        f32x4 x0 = *(const f32x4*)(qp)      * S2;
        f32x4 x1 = *(const f32x4*)(qp + 4)  * S2;
        f32x4 x2 = *(const f32x4*)(qp + 32) * S2;
        f32x4 x3 = *(const f32x4*)(qp + 36) * S2;
        bq0 = pack8(x0, x1);
        bq1 = pack8(x2, x3);
    }

    const char* kb_base = (const char*)kbf + (long)bh * SS * 128;    // 128 B / key
    const char* vt_base = (const char*)vtbf + (long)bh * 64 * 4096;  // 4096 B / d-row
    const int soff = wid * 2048 + lane * 16;

    auto issueK = [&](int kt, int b) {
        const char* gsrc = kb_base + (long)kt * 128 + soff;
        char* ldst = (char*)&Kl[b][0][0] + wid * 2048;
        gload16(gsrc, ldst);
        gload16(gsrc + 1024, ldst + 1024);
    };
    auto issueV = [&](int kt, int b) {
        #pragma unroll
        for (int j = 0; j < 2; ++j) {
            const int off = soff + j * 1024;
            const char* gsrc = vt_base + (long)(off >> 7) * 4096 + (long)kt * 2 + (off & 127);
            gload16(gsrc, (char*)&Vt[b][0][0] + wid * 2048 + j * 1024);
        }
    };

    // ---------------- pass 1: row sums of exp2(score) ----------------
    float lsum = 0.f;
    issueK(0, 0);
    wait_vm0(); bar_raw();
    for (int it = 0; it < 32; ++it) {
        const int p = it & 1;
        issueK(((it + 1) & 31) * 64, p ^ 1);
        wait_vm2(); bar_raw();               // tile it in LDS for all waves
        #pragma unroll
        for (int t = 0; t < 4; ++t) {
            const int row = t * 16 + c;
            const char* kr = (const char*)&Kl[p][row][0];
            const int x = (row & 3) << 5;
            bfx8 ka = *(const bfx8*)(kr + ((16 * g) ^ x));
            bfx8 kb = *(const bfx8*)(kr + ((64 + 16 * g) ^ x));
            f32x4 s = {0.f, 0.f, 0.f, 0.f};
            s = __builtin_amdgcn_mfma_f32_16x16x32_bf16(ka, bq0, s, 0, 0, 0);
            s = __builtin_amdgcn_mfma_f32_16x16x32_bf16(kb, bq1, s, 0, 0, 0);
            lsum += __builtin_amdgcn_exp2f(s[0]);
            lsum += __builtin_amdgcn_exp2f(s[1]);
            lsum += __builtin_amdgcn_exp2f(s[2]);
            lsum += __builtin_amdgcn_exp2f(s[3]);
        }
        bar_raw();                            // reads done; next iter may overwrite
    }
    lsum += __shfl_xor(lsum, 16, 64);
    lsum += __shfl_xor(lsum, 32, 64);
    const float invl = 1.0f / lsum;

    // ---------------- pass 2: attn (NT, coalesced) + PV ----------------
    f32x4 acc[4];
    #pragma unroll
    for (int i = 0; i < 4; ++i) acc[i] = (f32x4){0.f, 0.f, 0.f, 0.f};

    float* attnw = attn + (long)bh * SS * SS + (long)(qt * 64 + wid * 16) * SS;

    // K tile0 already in flight into Kl[0] (pass-1 wrap issue); add V tile0.
    issueV(0, 0);
    wait_vm0(); bar_raw();
    for (int it = 0; it < 32; ++it) {
        const int p  = it & 1;
        const int k0 = it * 64;
        const int nk = ((it + 1) & 31) * 64;
        issueK(nk, p ^ 1);
        issueV(nk, p ^ 1);
        wait_vm8();                           // retires tile-it loads; NT stores + new loads stream
        bar_raw();

        #pragma unroll
        for (int half = 0; half < 2; ++half) {
            #pragma unroll
            for (int tt = 0; tt < 2; ++tt) {
                const int t = half * 2 + tt;
                const int row = t * 16 + c;
                const char* kr = (const char*)&Kl[p][row][0];
                const int x = (row & 3) << 5;
                bfx8 ka = *(const bfx8*)(kr + ((16 * g) ^ x));
                bfx8 kb = *(const bfx8*)(kr + ((64 + 16 * g) ^ x));
                f32x4 s = {0.f, 0.f, 0.f, 0.f};
                s = __builtin_amdgcn_mfma_f32_16x16x32_bf16(ka, bq0, s, 0, 0, 0);
                s = __builtin_amdgcn_mfma_f32_16x16x32_bf16(kb, bq1, s, 0, 0, 0);
                bfx4 wp;
                wp[0] = f2bf(__builtin_amdgcn_exp2f(s[0]) * invl);
                wp[1] = f2bf(__builtin_amdgcn_exp2f(s[1]) * invl);
                wp[2] = f2bf(__builtin_amdgcn_exp2f(s[2]) * invl);
                wp[3] = f2bf(__builtin_amdgcn_exp2f(s[3]) * invl);
                *(bfx4*)&Wc[wid][c][t * 16 + 4 * g] = wp;
            }
            // PV over this 32-key half (wave-private Wc, lgkm-ordered)
            bfx8 wb = *(const bfx8*)((const char*)&Wc[wid][c][0] + half * 64 + 16 * g);
            #pragma unroll
            for (int ds = 0; ds < 4; ++ds) {
                const int vrow = ds * 16 + c;
                bfx8 va = *(const bfx8*)((const char*)&Vt[p][vrow][0] +
                                         ((half * 64 + 16 * g) ^ ((vrow & 3) << 5)));
                acc[ds] = __builtin_amdgcn_mfma_f32_16x16x32_bf16(va, wb, acc[ds], 0, 0, 0);
            }
        }

        // coalesced NT emit: 16 rows x 256 B contiguous (4 rows / instruction)
        {
            const int col4 = c * 4;
            #pragma unroll
            for (int rg = 0; rg < 4; ++rg) {
                const int r = rg * 4 + g;
                bfx4 w4 = *(const bfx4*)&Wc[wid][r][col4];
                f32x4 o;
                o[0] = bf2f(w4[0]); o[1] = bf2f(w4[1]);
                o[2] = bf2f(w4[2]); o[3] = bf2f(w4[3]);
                __builtin_nontemporal_store(o, (f32x4*)(attnw + (long)r * SS + k0 + col4));
            }
        }
        bar_raw();                            // all waves done reading tile it
    }

    // ---------------- row-norm preconditioning + output ----------------
    float ssq = 0.f;
    #pragma unroll
    for (int ds = 0; ds < 4; ++ds)
        #pragma unroll
        for (int r = 0; r < 4; ++r)
            ssq += acc[ds][r] * acc[ds][r];
    ssq += __shfl_xor(ssq, 16, 64);
    ssq += __shfl_xor(ssq, 32, 64);
    const float inv = 1.0f / (sqrtf(ssq) + 1e-8f);

    float* op = out + hoff + (long)qrow * DD;
    #pragma unroll
    for (int ds = 0; ds < 4; ++ds) {
        f32x4 o;
        o[0] = acc[ds][0] * inv; o[1] = acc[ds][1] * inv;
        o[2] = acc[ds][2] * inv; o[3] = acc[ds][3] * inv;
        *(f32x4*)&op[ds * 16 + 4 * g] = o;
    }
}

// ================= fallback (round-7 kernel, verbatim) =================
__device__ __forceinline__ void fb_bar_lg() {
    asm volatile("s_waitcnt lgkmcnt(0)\n\ts_barrier" ::: "memory");
    __builtin_amdgcn_sched_barrier(0);
}
__global__ __launch_bounds__(256, 3) void pattn_fallback(
    const float* __restrict__ q, const float* __restrict__ k,
    const float* __restrict__ v, float* __restrict__ out,
    float* __restrict__ attn)
{
    const int blk = blockIdx.x;
    const int bh  = (blk & 7) * 4 + ((blk >> 3) & 3);
    const int qt  = blk >> 5;
    const int tid = threadIdx.x;
    const int wid = tid >> 6, lane = tid & 63;
    const int c = lane & 15, g = lane >> 4;

    const long hoff = (long)bh * SS * DD;
    const int  qrow = qt * 64 + wid * 16 + c;

    __shared__ __align__(16) short Kl[128][72];
    __shared__ __align__(16) short Vt[64][136];
    __shared__ __align__(16) short Wc[4][16][136];

    bfx8 bq0, bq1;
    {
        const float* qp = q + hoff + (long)qrow * DD + 8 * g;
        f32x4 x0 = *(const f32x4*)(qp)      * S2;
        f32x4 x1 = *(const f32x4*)(qp + 4)  * S2;
        f32x4 x2 = *(const f32x4*)(qp + 32) * S2;
        f32x4 x3 = *(const f32x4*)(qp + 36) * S2;
        bq0 = pack8(x0, x1);
        bq1 = pack8(x2, x3);
    }

    const int skey = tid >> 1, sdh = (tid & 1) << 5;
    const int vkq  = (tid & 31) * 4, vdg = (tid >> 5) * 8;
    f32x4 kr[8], vr[8];

    auto loadK = [&](int k0) {
        const float* kp = k + hoff + (long)(k0 + skey) * DD + sdh;
        #pragma unroll
        for (int i = 0; i < 8; ++i) kr[i] = *(const f32x4*)(kp + 4 * i);
    };
    auto writeK = [&]() {
        *(bfx8*)&Kl[skey][sdh + 0]  = pack8(kr[0], kr[1]);
        *(bfx8*)&Kl[skey][sdh + 8]  = pack8(kr[2], kr[3]);
        *(bfx8*)&Kl[skey][sdh + 16] = pack8(kr[4], kr[5]);
        *(bfx8*)&Kl[skey][sdh + 24] = pack8(kr[6], kr[7]);
    };
    auto loadV = [&](int k0) {
        const float* vp = v + hoff + (long)(k0 + vkq) * DD + vdg;
        #pragma unroll
        for (int r = 0; r < 4; ++r) {
            vr[2 * r]     = *(const f32x4*)(vp + r * DD);
            vr[2 * r + 1] = *(const f32x4*)(vp + r * DD + 4);
        }
    };
    auto writeV = [&]() {
        #pragma unroll
        for (int d = 0; d < 4; ++d) {
            bfx4 w;
            w[0] = f2bf(vr[0][d]); w[1] = f2bf(vr[2][d]);
            w[2] = f2bf(vr[4][d]); w[3] = f2bf(vr[6][d]);
            *(bfx4*)&Vt[vdg + d][vkq] = w;
        }
        #pragma unroll
        for (int d = 0; d < 4; ++d) {
            bfx4 w;
            w[0] = f2bf(vr[1][d]); w[1] = f2bf(vr[3][d]);
            w[2] = f2bf(vr[5][d]); w[3] = f2bf(vr[7][d]);
            *(bfx4*)&Vt[vdg + 4 + d][vkq] = w;
        }
    };

    float lsum = 0.f;
    loadK(0); wait_vm0(); writeK();
    for (int it = 0; it < 16; ++it) {
        fb_bar_lg();
        if (it < 15) loadK((it + 1) * 128);
        #pragma unroll
        for (int T = 0; T < 8; ++T) {
            bfx8 ka = *(const bfx8*)&Kl[T * 16 + c][8 * g];
            bfx8 kb = *(const bfx8*)&Kl[T * 16 + c][32 + 8 * g];
            f32x4 s = {0.f, 0.f, 0.f, 0.f};
            s = __builtin_amdgcn_mfma_f32_16x16x32_bf16(ka, bq0, s, 0, 0, 0);
            s = __builtin_amdgcn_mfma_f32_16x16x32_bf16(kb, bq1, s, 0, 0, 0);
            lsum += __builtin_amdgcn_exp2f(s[0]);
            lsum += __builtin_amdgcn_exp2f(s[1]);
            lsum += __builtin_amdgcn_exp2f(s[2]);
            lsum += __builtin_amdgcn_exp2f(s[3]);
        }
        if (it < 15) wait_vm0();
        bar_raw();
        if (it < 15) writeK();
    }
    lsum += __shfl_xor(lsum, 16, 64);
    lsum += __shfl_xor(lsum, 32, 64);
    const float invl = 1.0f / lsum;

    f32x4 acc[4];
    #pragma unroll
    for (int i = 0; i < 4; ++i) acc[i] = (f32x4){0.f, 0.f, 0.f, 0.f};

    float* attnw = attn + (long)bh * SS * SS + (long)(qt * 64 + wid * 16) * SS;

    loadK(0); loadV(0);
    wait_vm0();
    bar_raw();
    writeK(); writeV();
    for (int it = 0; it < 16; ++it) {
        const int k0 = it * 128;
        fb_bar_lg();
        if (it < 15) { loadK(k0 + 128); loadV(k0 + 128); }

        #pragma unroll
        for (int G = 0; G < 4; ++G) {
            #pragma unroll
            for (int t = 0; t < 2; ++t) {
                const int kb2 = G * 32 + t * 16;
                bfx8 ka = *(const bfx8*)&Kl[kb2 + c][8 * g];
                bfx8 kb = *(const bfx8*)&Kl[kb2 + c][32 + 8 * g];
                f32x4 s = {0.f, 0.f, 0.f, 0.f};
                s = __builtin_amdgcn_mfma_f32_16x16x32_bf16(ka, bq0, s, 0, 0, 0);
                s = __builtin_amdgcn_mfma_f32_16x16x32_bf16(kb, bq1, s, 0, 0, 0);
                bfx4 wp;
                wp[0] = f2bf(__builtin_amdgcn_exp2f(s[0]) * invl);
                wp[1] = f2bf(__builtin_amdgcn_exp2f(s[1]) * invl);
                wp[2] = f2bf(__builtin_amdgcn_exp2f(s[2]) * invl);
                wp[3] = f2bf(__builtin_amdgcn_exp2f(s[3]) * invl);
                *(bfx4*)&Wc[wid][c][kb2 + 4 * g] = wp;
            }
            bfx8 wb = *(const bfx8*)&Wc[wid][c][G * 32 + 8 * g];
            #pragma unroll
            for (int ds = 0; ds < 4; ++ds) {
                bfx8 va = *(const bfx8*)&Vt[ds * 16 + c][G * 32 + 8 * g];
                acc[ds] = __builtin_amdgcn_mfma_f32_16x16x32_bf16(va, wb, acc[ds], 0, 0, 0);
            }
        }

        {
            const int half = lane >> 5;
            const int col  = (lane & 31) * 4;
            #pragma unroll
            for (int rg = 0; rg < 8; ++rg) {
                const int r = rg * 2 + half;
                bfx4 w4 = *(const bfx4*)&Wc[wid][r][col];
                f32x4 o;
                o[0] = bf2f(w4[0]); o[1] = bf2f(w4[1]);
                o[2] = bf2f(w4[2]); o[3] = bf2f(w4[3]);
                __builtin_nontemporal_store(o, (f32x4*)(attnw + (long)r * SS + k0 + col));
            }
        }

        if (it < 15) {
            wait_vm8();
            bar_raw();
            writeK(); writeV();
        }
    }

    float ssq = 0.f;
    #pragma unroll
    for (int ds = 0; ds < 4; ++ds)
        #pragma unroll
        for (int r = 0; r < 4; ++r)
            ssq += acc[ds][r] * acc[ds][r];
    ssq += __shfl_xor(ssq, 16, 64);
    ssq += __shfl_xor(ssq, 32, 64);
    const float inv = 1.0f / (sqrtf(ssq) + 1e-8f);

    float* op = out + hoff + (long)qrow * DD;
    #pragma unroll
    for (int ds = 0; ds < 4; ++ds) {
        f32x4 o;
        o[0] = acc[ds][0] * inv; o[1] = acc[ds][1] * inv;
        o[2] = acc[ds][2] * inv; o[3] = acc[ds][3] * inv;
        *(f32x4*)&op[ds * 16 + 4 * g] = o;
    }
}

extern "C" void kernel_launch(void* const* d_in, const int* in_sizes, int n_in,
                              void* d_out, int out_size, void* d_ws, size_t ws_size,
                              hipStream_t stream) {
    const float* q = (const float*)d_in[0];
    const float* k = (const float*)d_in[1];
    const float* v = (const float*)d_in[2];
    float* out  = (float*)d_out;
    float* attn = out + (long)2 * 16 * SS * DD;

    const size_t need = 2UL * 32 * SS * DD * sizeof(short);   // 16.8 MB
    if (ws_size >= need) {
        short* kbf  = (short*)d_ws;
        short* vtbf = kbf + (size_t)32 * SS * DD;
        hipLaunchKernelGGL(prep_kernel, dim3(512), dim3(256), 0, stream, k, v, kbf, vtbf);
        hipLaunchKernelGGL(pattn_main, dim3(1024), dim3(256), 0, stream, q, kbf, vtbf, out, attn);
    } else {
        hipLaunchKernelGGL(pattn_fallback, dim3(1024), dim3(256), 0, stream, q, k, v, out, attn);
    }
}

// Round 9
// 173.142 us; speedup vs baseline: 1.9548x; 1.1091x over previous
//
#include <hip/hip_runtime.h>

#define SS 2048
#define DD 64
#define S2 0.18033688011112042f   // (1/sqrt(64)) * log2(e)

typedef __attribute__((ext_vector_type(4))) float f32x4;
typedef __attribute__((ext_vector_type(8))) short bfx8;
typedef __attribute__((ext_vector_type(4))) short bfx4;

__device__ __forceinline__ short f2bf(float f) {
    unsigned u = __builtin_bit_cast(unsigned, f);
    u += 0x7fffu + ((u >> 16) & 1u);   // RTNE
    return (short)(u >> 16);
}
__device__ __forceinline__ bfx8 pack8(f32x4 a, f32x4 b) {
    bfx8 r;
    r[0] = f2bf(a[0]); r[1] = f2bf(a[1]); r[2] = f2bf(a[2]); r[3] = f2bf(a[3]);
    r[4] = f2bf(b[0]); r[5] = f2bf(b[1]); r[6] = f2bf(b[2]); r[7] = f2bf(b[3]);
    return r;
}
__device__ __forceinline__ float bf2f(short s) {
    unsigned u = ((unsigned)(unsigned short)s) << 16;
    return __builtin_bit_cast(float, u);
}
__device__ __forceinline__ void bar_raw() {
    asm volatile("s_barrier" ::: "memory");
    __builtin_amdgcn_sched_barrier(0);
}
__device__ __forceinline__ void wait_vm0() {
    asm volatile("s_waitcnt vmcnt(0)" ::: "memory");
    __builtin_amdgcn_sched_barrier(0);
}
__device__ __forceinline__ void wait_vm2() {
    asm volatile("s_waitcnt vmcnt(2)" ::: "memory");
    __builtin_amdgcn_sched_barrier(0);
}
__device__ __forceinline__ void wait_vm8() {
    asm volatile("s_waitcnt vmcnt(8)" ::: "memory");
    __builtin_amdgcn_sched_barrier(0);
}
// async global->LDS, 16B per lane; lds dest = wave-uniform base + lane*16
__device__ __forceinline__ void gload16(const void* g, void* l) {
    __builtin_amdgcn_global_load_lds(
        (const __attribute__((address_space(1))) unsigned*)g,
        (__attribute__((address_space(3))) unsigned*)l, 16, 0, 0);
}

// ================= pre-kernel: K -> bf16 [key][64], V -> bf16^T [d][key] =================
// Both stored granule-swizzled: 16B granule at in-row byte p holds original bytes p^((row&3)<<5).
__global__ __launch_bounds__(256) void prep_kernel(
    const float* __restrict__ k, const float* __restrict__ v,
    short* __restrict__ kbf, short* __restrict__ vtbf)
{
    const int blk = blockIdx.x;          // 512 = 32 bh x 16 chunks of 128 keys
    const int bh = blk >> 4, kc = blk & 15;
    const int tid = threadIdx.x;
    const long hoff = (long)bh * SS * DD;

    {   // K convert (swizzled within each 128B key-row)
        const int key = tid >> 1, h = tid & 1;
        const float* kp = k + hoff + (long)(kc * 128 + key) * DD + h * 32;
        char* krow = (char*)kbf + ((long)bh * SS + kc * 128 + key) * 128;
        const int x = (key & 3) << 5;
        #pragma unroll
        for (int i = 0; i < 4; ++i) {
            f32x4 a = *(const f32x4*)(kp + i * 8);
            f32x4 b = *(const f32x4*)(kp + i * 8 + 4);
            *(bfx8*)(krow + ((h * 64 + i * 16) ^ x)) = pack8(a, b);
        }
    }

    __shared__ __align__(16) short Vl[64][136];
    {   // V transpose via LDS
        const int kq = (tid & 31) * 4, dg = (tid >> 5) * 8;
        const float* vp = v + hoff + (long)(kc * 128 + kq) * DD + dg;
        f32x4 r0a = *(const f32x4*)(vp),        r0b = *(const f32x4*)(vp + 4);
        f32x4 r1a = *(const f32x4*)(vp + DD),   r1b = *(const f32x4*)(vp + DD + 4);
        f32x4 r2a = *(const f32x4*)(vp + 2*DD), r2b = *(const f32x4*)(vp + 2*DD + 4);
        f32x4 r3a = *(const f32x4*)(vp + 3*DD), r3b = *(const f32x4*)(vp + 3*DD + 4);
        #pragma unroll
        for (int d = 0; d < 4; ++d) {
            bfx4 w;
            w[0] = f2bf(r0a[d]); w[1] = f2bf(r1a[d]);
            w[2] = f2bf(r2a[d]); w[3] = f2bf(r3a[d]);
            *(bfx4*)&Vl[dg + d][kq] = w;
        }
        #pragma unroll
        for (int d = 0; d < 4; ++d) {
            bfx4 w;
            w[0] = f2bf(r0b[d]); w[1] = f2bf(r1b[d]);
            w[2] = f2bf(r2b[d]); w[3] = f2bf(r3b[d]);
            *(bfx4*)&Vl[dg + 4 + d][kq] = w;
        }
    }
    __syncthreads();
    {
        const int d = tid >> 2, quar = tid & 3;
        char* vrow = (char*)vtbf + ((long)bh * 64 + d) * 4096 + kc * 256;
        const int x = (d & 3) << 5;
        #pragma unroll
        for (int i = 0; i < 4; ++i) {
            bfx8 w = *(const bfx8*)((const char*)&Vl[d][0] + quar * 64 + i * 16);
            *(bfx8*)(vrow + ((quar * 64 + i * 16) ^ x)) = w;
        }
    }
}

// ================= main kernel: 32 q-rows/wave, gl_lds staged, dbuf 64-key tiles =================
__global__ __launch_bounds__(256, 2) void pattn_main2(
    const float* __restrict__ q, const short* __restrict__ kbf,
    const short* __restrict__ vtbf, float* __restrict__ out,
    float* __restrict__ attn)
{
    // XCD-grouped mapping (validated r5). grid 512: qt in [0,16), 128 q-rows/block.
    const int blk = blockIdx.x;
    const int bh  = (blk & 7) * 4 + ((blk >> 3) & 3);
    const int qt  = blk >> 5;
    const int tid = threadIdx.x;
    const int wid = tid >> 6, lane = tid & 63;
    const int c = lane & 15, g = lane >> 4;

    __shared__ __align__(16) short Kl[2][64][64];   // 16384 B
    __shared__ __align__(16) short Vt[2][64][64];   // 16384 B
    __shared__ __align__(16) short Wc[4][32][80];   // 20480 B  -> 53248 B total

    const long hoff = (long)bh * SS * DD;
    const int  qA = qt * 128 + wid * 32 + c;   // frag-A q row
    const int  qB = qA + 16;                   // frag-B q row

    bfx8 bqA0, bqA1, bqB0, bqB1;
    {
        const float* qp = q + hoff + (long)qA * DD + 8 * g;
        bqA0 = pack8(*(const f32x4*)(qp)      * S2, *(const f32x4*)(qp + 4)  * S2);
        bqA1 = pack8(*(const f32x4*)(qp + 32) * S2, *(const f32x4*)(qp + 36) * S2);
        const float* qp2 = q + hoff + (long)qB * DD + 8 * g;
        bqB0 = pack8(*(const f32x4*)(qp2)      * S2, *(const f32x4*)(qp2 + 4)  * S2);
        bqB1 = pack8(*(const f32x4*)(qp2 + 32) * S2, *(const f32x4*)(qp2 + 36) * S2);
    }

    const char* kb_base = (const char*)kbf + (long)bh * SS * 128;    // 128 B / key
    const char* vt_base = (const char*)vtbf + (long)bh * 64 * 4096;  // 4096 B / d-row
    const int soff = wid * 2048 + lane * 16;

    auto issueK = [&](int kt, int b) {
        const char* gsrc = kb_base + (long)kt * 128 + soff;
        char* ldst = (char*)&Kl[b][0][0] + wid * 2048;
        gload16(gsrc, ldst);
        gload16(gsrc + 1024, ldst + 1024);
    };
    auto issueV = [&](int kt, int b) {
        #pragma unroll
        for (int j = 0; j < 2; ++j) {
            const int off = soff + j * 1024;
            const char* gsrc = vt_base + (long)(off >> 7) * 4096 + (long)kt * 2 + (off & 127);
            gload16(gsrc, (char*)&Vt[b][0][0] + wid * 2048 + j * 1024);
        }
    };

    // ---------------- pass 1: row sums of exp2(score) ----------------
    float lsA[4] = {0.f,0.f,0.f,0.f}, lsB[4] = {0.f,0.f,0.f,0.f};
    issueK(0, 0);
    wait_vm0(); bar_raw();
    for (int it = 0; it < 32; ++it) {
        const int p = it & 1;
        issueK(((it + 1) & 31) * 64, p ^ 1);
        wait_vm2(); bar_raw();
        #pragma unroll
        for (int t = 0; t < 4; ++t) {
            const int row = t * 16 + c;
            const char* kr = (const char*)&Kl[p][row][0];
            const int x = (row & 3) << 5;
            bfx8 ka = *(const bfx8*)(kr + ((16 * g) ^ x));
            bfx8 kb = *(const bfx8*)(kr + ((64 + 16 * g) ^ x));
            f32x4 sA = {0.f,0.f,0.f,0.f}, sB = {0.f,0.f,0.f,0.f};
            sA = __builtin_amdgcn_mfma_f32_16x16x32_bf16(ka, bqA0, sA, 0, 0, 0);
            sA = __builtin_amdgcn_mfma_f32_16x16x32_bf16(kb, bqA1, sA, 0, 0, 0);
            sB = __builtin_amdgcn_mfma_f32_16x16x32_bf16(ka, bqB0, sB, 0, 0, 0);
            sB = __builtin_amdgcn_mfma_f32_16x16x32_bf16(kb, bqB1, sB, 0, 0, 0);
            #pragma unroll
            for (int r = 0; r < 4; ++r) {
                lsA[r] += __builtin_amdgcn_exp2f(sA[r]);
                lsB[r] += __builtin_amdgcn_exp2f(sB[r]);
            }
        }
        bar_raw();
    }
    float lsumA = (lsA[0] + lsA[1]) + (lsA[2] + lsA[3]);
    float lsumB = (lsB[0] + lsB[1]) + (lsB[2] + lsB[3]);
    lsumA += __shfl_xor(lsumA, 16, 64);
    lsumA += __shfl_xor(lsumA, 32, 64);
    lsumB += __shfl_xor(lsumB, 16, 64);
    lsumB += __shfl_xor(lsumB, 32, 64);
    const float invlA = 1.0f / lsumA;
    const float invlB = 1.0f / lsumB;

    // ---------------- pass 2: attn (NT, coalesced) + PV ----------------
    f32x4 accA[4], accB[4];
    #pragma unroll
    for (int i = 0; i < 4; ++i) { accA[i] = (f32x4){0.f,0.f,0.f,0.f}; accB[i] = (f32x4){0.f,0.f,0.f,0.f}; }

    float* attnw = attn + (long)bh * SS * SS + (long)(qt * 128 + wid * 32) * SS;

    // K tile0 already in flight into Kl[0] (pass-1 wrap issue); add V tile0.
    issueV(0, 0);
    wait_vm0(); bar_raw();
    for (int it = 0; it < 32; ++it) {
        const int p  = it & 1;
        const int k0 = it * 64;
        const int nk = ((it + 1) & 31) * 64;
        issueK(nk, p ^ 1);
        issueV(nk, p ^ 1);
        wait_vm8();                 // tile-it loads retired; stores + next loads stream
        bar_raw();

        #pragma unroll
        for (int half = 0; half < 2; ++half) {
            #pragma unroll
            for (int tt = 0; tt < 2; ++tt) {
                const int t = half * 2 + tt;
                const int row = t * 16 + c;
                const char* kr = (const char*)&Kl[p][row][0];
                const int x = (row & 3) << 5;
                bfx8 ka = *(const bfx8*)(kr + ((16 * g) ^ x));
                bfx8 kb = *(const bfx8*)(kr + ((64 + 16 * g) ^ x));
                f32x4 sA = {0.f,0.f,0.f,0.f}, sB = {0.f,0.f,0.f,0.f};
                sA = __builtin_amdgcn_mfma_f32_16x16x32_bf16(ka, bqA0, sA, 0, 0, 0);
                sA = __builtin_amdgcn_mfma_f32_16x16x32_bf16(kb, bqA1, sA, 0, 0, 0);
                sB = __builtin_amdgcn_mfma_f32_16x16x32_bf16(ka, bqB0, sB, 0, 0, 0);
                sB = __builtin_amdgcn_mfma_f32_16x16x32_bf16(kb, bqB1, sB, 0, 0, 0);
                bfx4 wpA, wpB;
                #pragma unroll
                for (int r = 0; r < 4; ++r) {
                    wpA[r] = f2bf(__builtin_amdgcn_exp2f(sA[r]) * invlA);
                    wpB[r] = f2bf(__builtin_amdgcn_exp2f(sB[r]) * invlB);
                }
                *(bfx4*)&Wc[wid][c][t * 16 + 4 * g]      = wpA;
                *(bfx4*)&Wc[wid][16 + c][t * 16 + 4 * g] = wpB;
            }
            // PV over this 32-key half (wave-private Wc, lgkm-ordered)
            bfx8 wbA = *(const bfx8*)((const char*)&Wc[wid][c][0]      + half * 64 + 16 * g);
            bfx8 wbB = *(const bfx8*)((const char*)&Wc[wid][16 + c][0] + half * 64 + 16 * g);
            #pragma unroll
            for (int ds = 0; ds < 4; ++ds) {
                const int vrow = ds * 16 + c;
                bfx8 va = *(const bfx8*)((const char*)&Vt[p][vrow][0] +
                                         ((half * 64 + 16 * g) ^ ((vrow & 3) << 5)));
                accA[ds] = __builtin_amdgcn_mfma_f32_16x16x32_bf16(va, wbA, accA[ds], 0, 0, 0);
                accB[ds] = __builtin_amdgcn_mfma_f32_16x16x32_bf16(va, wbB, accB[ds], 0, 0, 0);
            }
        }

        // coalesced NT emit: 32 rows x 256 B contiguous (4 rows / instruction)
        {
            const int col4 = c * 4;
            #pragma unroll
            for (int rg = 0; rg < 8; ++rg) {
                const int r = rg * 4 + g;
                bfx4 w4 = *(const bfx4*)&Wc[wid][r][col4];
                f32x4 o;
                o[0] = bf2f(w4[0]); o[1] = bf2f(w4[1]);
                o[2] = bf2f(w4[2]); o[3] = bf2f(w4[3]);
                __builtin_nontemporal_store(o, (f32x4*)(attnw + (long)r * SS + k0 + col4));
            }
        }
        bar_raw();
    }

    // ---------------- row-norm preconditioning + output ----------------
    float ssqA = 0.f, ssqB = 0.f;
    #pragma unroll
    for (int ds = 0; ds < 4; ++ds)
        #pragma unroll
        for (int r = 0; r < 4; ++r) { ssqA += accA[ds][r] * accA[ds][r]; ssqB += accB[ds][r] * accB[ds][r]; }
    ssqA += __shfl_xor(ssqA, 16, 64);
    ssqA += __shfl_xor(ssqA, 32, 64);
    ssqB += __shfl_xor(ssqB, 16, 64);
    ssqB += __shfl_xor(ssqB, 32, 64);
    const float invA = 1.0f / (sqrtf(ssqA) + 1e-8f);
    const float invB = 1.0f / (sqrtf(ssqB) + 1e-8f);

    float* opA = out + hoff + (long)qA * DD;
    float* opB = out + hoff + (long)qB * DD;
    #pragma unroll
    for (int ds = 0; ds < 4; ++ds) {
        f32x4 oA, oB;
        #pragma unroll
        for (int r = 0; r < 4; ++r) { oA[r] = accA[ds][r] * invA; oB[r] = accB[ds][r] * invB; }
        *(f32x4*)&opA[ds * 16 + 4 * g] = oA;
        *(f32x4*)&opB[ds * 16 + 4 * g] = oB;
    }
}

// ================= fallback (round-7 kernel, verbatim) =================
__device__ __forceinline__ void fb_bar_lg() {
    asm volatile("s_waitcnt lgkmcnt(0)\n\ts_barrier" ::: "memory");
    __builtin_amdgcn_sched_barrier(0);
}
__global__ __launch_bounds__(256, 3) void pattn_fallback(
    const float* __restrict__ q, const float* __restrict__ k,
    const float* __restrict__ v, float* __restrict__ out,
    float* __restrict__ attn)
{
    const int blk = blockIdx.x;
    const int bh  = (blk & 7) * 4 + ((blk >> 3) & 3);
    const int qt  = blk >> 5;
    const int tid = threadIdx.x;
    const int wid = tid >> 6, lane = tid & 63;
    const int c = lane & 15, g = lane >> 4;

    const long hoff = (long)bh * SS * DD;
    const int  qrow = qt * 64 + wid * 16 + c;

    __shared__ __align__(16) short Kl[128][72];
    __shared__ __align__(16) short Vt[64][136];
    __shared__ __align__(16) short Wc[4][16][136];

    bfx8 bq0, bq1;
    {
        const float* qp = q + hoff + (long)qrow * DD + 8 * g;
        f32x4 x0 = *(const f32x4*)(qp)      * S2;
        f32x4 x1 = *(const f32x4*)(qp + 4)  * S2;
        f32x4 x2 = *(const f32x4*)(qp + 32) * S2;
        f32x4 x3 = *(const f32x4*)(qp + 36) * S2;
        bq0 = pack8(x0, x1);
        bq1 = pack8(x2, x3);
    }

    const int skey = tid >> 1, sdh = (tid & 1) << 5;
    const int vkq  = (tid & 31) * 4, vdg = (tid >> 5) * 8;
    f32x4 kr[8], vr[8];

    auto loadK = [&](int k0) {
        const float* kp = k + hoff + (long)(k0 + skey) * DD + sdh;
        #pragma unroll
        for (int i = 0; i < 8; ++i) kr[i] = *(const f32x4*)(kp + 4 * i);
    };
    auto writeK = [&]() {
        *(bfx8*)&Kl[skey][sdh + 0]  = pack8(kr[0], kr[1]);
        *(bfx8*)&Kl[skey][sdh + 8]  = pack8(kr[2], kr[3]);
        *(bfx8*)&Kl[skey][sdh + 16] = pack8(kr[4], kr[5]);
        *(bfx8*)&Kl[skey][sdh + 24] = pack8(kr[6], kr[7]);
    };
    auto loadV = [&](int k0) {
        const float* vp = v + hoff + (long)(k0 + vkq) * DD + vdg;
        #pragma unroll
        for (int r = 0; r < 4; ++r) {
            vr[2 * r]     = *(const f32x4*)(vp + r * DD);
            vr[2 * r + 1] = *(const f32x4*)(vp + r * DD + 4);
        }
    };
    auto writeV = [&]() {
        #pragma unroll
        for (int d = 0; d < 4; ++d) {
            bfx4 w;
            w[0] = f2bf(vr[0][d]); w[1] = f2bf(vr[2][d]);
            w[2] = f2bf(vr[4][d]); w[3] = f2bf(vr[6][d]);
            *(bfx4*)&Vt[vdg + d][vkq] = w;
        }
        #pragma unroll
        for (int d = 0; d < 4; ++d) {
            bfx4 w;
            w[0] = f2bf(vr[1][d]); w[1] = f2bf(vr[3][d]);
            w[2] = f2bf(vr[5][d]); w[3] = f2bf(vr[7][d]);
            *(bfx4*)&Vt[vdg + 4 + d][vkq] = w;
        }
    };

    float lsum = 0.f;
    loadK(0); wait_vm0(); writeK();
    for (int it = 0; it < 16; ++it) {
        fb_bar_lg();
        if (it < 15) loadK((it + 1) * 128);
        #pragma unroll
        for (int T = 0; T < 8; ++T) {
            bfx8 ka = *(const bfx8*)&Kl[T * 16 + c][8 * g];
            bfx8 kb = *(const bfx8*)&Kl[T * 16 + c][32 + 8 * g];
            f32x4 s = {0.f, 0.f, 0.f, 0.f};
            s = __builtin_amdgcn_mfma_f32_16x16x32_bf16(ka, bq0, s, 0, 0, 0);
            s = __builtin_amdgcn_mfma_f32_16x16x32_bf16(kb, bq1, s, 0, 0, 0);
            lsum += __builtin_amdgcn_exp2f(s[0]);
            lsum += __builtin_amdgcn_exp2f(s[1]);
            lsum += __builtin_amdgcn_exp2f(s[2]);
            lsum += __builtin_amdgcn_exp2f(s[3]);
        }
        if (it < 15) wait_vm0();
        bar_raw();
        if (it < 15) writeK();
    }
    lsum += __shfl_xor(lsum, 16, 64);
    lsum += __shfl_xor(lsum, 32, 64);
    const float invl = 1.0f / lsum;

    f32x4 acc[4];
    #pragma unroll
    for (int i = 0; i < 4; ++i) acc[i] = (f32x4){0.f, 0.f, 0.f, 0.f};

    float* attnw = attn + (long)bh * SS * SS + (long)(qt * 64 + wid * 16) * SS;

    loadK(0); loadV(0);
    wait_vm0();
    bar_raw();
    writeK(); writeV();
    for (int it = 0; it < 16; ++it) {
        const int k0 = it * 128;
        fb_bar_lg();
        if (it < 15) { loadK(k0 + 128); loadV(k0 + 128); }

        #pragma unroll
        for (int G = 0; G < 4; ++G) {
            #pragma unroll
            for (int t = 0; t < 2; ++t) {
                const int kb2 = G * 32 + t * 16;
                bfx8 ka = *(const bfx8*)&Kl[kb2 + c][8 * g];
                bfx8 kb = *(const bfx8*)&Kl[kb2 + c][32 + 8 * g];
                f32x4 s = {0.f, 0.f, 0.f, 0.f};
                s = __builtin_amdgcn_mfma_f32_16x16x32_bf16(ka, bq0, s, 0, 0, 0);
                s = __builtin_amdgcn_mfma_f32_16x16x32_bf16(kb, bq1, s, 0, 0, 0);
                bfx4 wp;
                wp[0] = f2bf(__builtin_amdgcn_exp2f(s[0]) * invl);
                wp[1] = f2bf(__builtin_amdgcn_exp2f(s[1]) * invl);
                wp[2] = f2bf(__builtin_amdgcn_exp2f(s[2]) * invl);
                wp[3] = f2bf(__builtin_amdgcn_exp2f(s[3]) * invl);
                *(bfx4*)&Wc[wid][c][kb2 + 4 * g] = wp;
            }
            bfx8 wb = *(const bfx8*)&Wc[wid][c][G * 32 + 8 * g];
            #pragma unroll
            for (int ds = 0; ds < 4; ++ds) {
                bfx8 va = *(const bfx8*)&Vt[ds * 16 + c][G * 32 + 8 * g];
                acc[ds] = __builtin_amdgcn_mfma_f32_16x16x32_bf16(va, wb, acc[ds], 0, 0, 0);
            }
        }

        {
            const int half = lane >> 5;
            const int col  = (lane & 31) * 4;
            #pragma unroll
            for (int rg = 0; rg < 8; ++rg) {
                const int r = rg * 2 + half;
                bfx4 w4 = *(const bfx4*)&Wc[wid][r][col];
                f32x4 o;
                o[0] = bf2f(w4[0]); o[1] = bf2f(w4[1]);
                o[2] = bf2f(w4[2]); o[3] = bf2f(w4[3]);
                __builtin_nontemporal_store(o, (f32x4*)(attnw + (long)r * SS + k0 + col));
            }
        }

        if (it < 15) {
            wait_vm8();
            bar_raw();
            writeK(); writeV();
        }
    }

    float ssq = 0.f;
    #pragma unroll
    for (int ds = 0; ds < 4; ++ds)
        #pragma unroll
        for (int r = 0; r < 4; ++r)
            ssq += acc[ds][r] * acc[ds][r];
    ssq += __shfl_xor(ssq, 16, 64);
    ssq += __shfl_xor(ssq, 32, 64);
    const float inv = 1.0f / (sqrtf(ssq) + 1e-8f);

    float* op = out + hoff + (long)qrow * DD;
    #pragma unroll
    for (int ds = 0; ds < 4; ++ds) {
        f32x4 o;
        o[0] = acc[ds][0] * inv; o[1] = acc[ds][1] * inv;
        o[2] = acc[ds][2] * inv; o[3] = acc[ds][3] * inv;
        *(f32x4*)&op[ds * 16 + 4 * g] = o;
    }
}

extern "C" void kernel_launch(void* const* d_in, const int* in_sizes, int n_in,
                              void* d_out, int out_size, void* d_ws, size_t ws_size,
                              hipStream_t stream) {
    const float* q = (const float*)d_in[0];
    const float* k = (const float*)d_in[1];
    const float* v = (const float*)d_in[2];
    float* out  = (float*)d_out;
    float* attn = out + (long)2 * 16 * SS * DD;

    const size_t need = 2UL * 32 * SS * DD * sizeof(short);   // 16.8 MB
    if (ws_size >= need) {
        short* kbf  = (short*)d_ws;
        short* vtbf = kbf + (size_t)32 * SS * DD;
        hipLaunchKernelGGL(prep_kernel, dim3(512), dim3(256), 0, stream, k, v, kbf, vtbf);
        hipLaunchKernelGGL(pattn_main2, dim3(512), dim3(256), 0, stream, q, kbf, vtbf, out, attn);
    } else {
        hipLaunchKernelGGL(pattn_fallback, dim3(1024), dim3(256), 0, stream, q, k, v, out, attn);
    }
}